// Round 2
// baseline (1751.494 us; speedup 1.0000x reference)
//
#include <hip/hip_runtime.h>
#include <math.h>

#define T_LEN 3000
#define HID 64

__device__ __forceinline__ float sigmoid_f(float v) {
    // 1/(1+exp(-v)); v_exp_f32 + v_rcp_f32, ~1e-6 rel err
    return __builtin_amdgcn_rcpf(1.0f + __expf(-v));
}
__device__ __forceinline__ float tanh_f(float v) {
    // tanh(v) = 2*sigmoid(2v) - 1; saturates correctly for |v| large
    return fmaf(2.0f, __builtin_amdgcn_rcpf(1.0f + __expf(-2.0f * v)), -1.0f);
}

__device__ __forceinline__ float bcast(float v, int lane) {
    return __int_as_float(__builtin_amdgcn_readlane(__float_as_int(v), lane));
}

// One wave per batch element. Lane g owns hidden unit g:
//  - W_hh rows g, 64+g, 128+g register-resident (192 VGPRs)
//  - h[g] in a VGPR; broadcast to all lanes via v_readlane (no LDS, no barrier)
//  - r/z/n for unit g computed entirely in-lane (r*(Whn.h) needs no cross-lane)
__global__ __launch_bounds__(64, 1) void gru_onewave(
    const float* __restrict__ x,     // (B, T, 1)
    const float* __restrict__ W_ih,  // (192, 1)
    const float* __restrict__ W_hh,  // (192, 64)
    const float* __restrict__ b_ih,  // (192,)
    const float* __restrict__ b_hh,  // (192,)
    const float* __restrict__ W_fc,  // (1, 64)
    const float* __restrict__ b_fc,  // (1,)
    float* __restrict__ out)         // (B,)
{
    const int b = blockIdx.x;
    const int g = threadIdx.x;  // 0..63, hidden unit index
    const long xbase = (long)b * T_LEN;

    // ---- one-time: W_hh rows for unit g into VGPRs ----
    float wr[HID], wz[HID], wn[HID];
    const float4* Wr4 = reinterpret_cast<const float4*>(W_hh + (size_t)(g)       * HID);
    const float4* Wz4 = reinterpret_cast<const float4*>(W_hh + (size_t)(64 + g)  * HID);
    const float4* Wn4 = reinterpret_cast<const float4*>(W_hh + (size_t)(128 + g) * HID);
#pragma unroll
    for (int i = 0; i < 16; ++i) {
        float4 a = Wr4[i]; wr[4*i] = a.x; wr[4*i+1] = a.y; wr[4*i+2] = a.z; wr[4*i+3] = a.w;
        float4 c = Wz4[i]; wz[4*i] = c.x; wz[4*i+1] = c.y; wz[4*i+2] = c.z; wz[4*i+3] = c.w;
        float4 d = Wn4[i]; wn[4*i] = d.x; wn[4*i+1] = d.y; wn[4*i+2] = d.z; wn[4*i+3] = d.w;
    }
    const float wihr = W_ih[g],        wihz = W_ih[64 + g],   wihn = W_ih[128 + g];
    const float br   = b_ih[g]      + b_hh[g];        // fold r biases
    const float bz   = b_ih[64 + g] + b_hh[64 + g];   // fold z biases
    const float bin  = b_ih[128 + g];                 // n input bias
    const float bhn  = b_hh[128 + g];                 // n hidden bias (inside r*(...))

    // ---- x chunk prefetch: lane j holds x[t0 + j]; broadcast via readlane ----
    float xcur = x[xbase + g];            // steps 0..63
    float xnxt = x[xbase + 64 + g];       // steps 64..127
    float h = 0.0f;                       // lane g holds h[g]

    for (int t = 0; t < T_LEN; ++t) {
        const int j = t & 63;
        const float xt = bcast(xcur, j);

        // ---- matvec: 3 dot products, h broadcast via readlane (SGPR operand) ----
        float ar = 0.f, az = 0.f, an = 0.f;
#pragma unroll
        for (int k = 0; k < HID; ++k) {
            const float hk = bcast(h, k);
            ar = fmaf(wr[k], hk, ar);
            az = fmaf(wz[k], hk, az);
            an = fmaf(wn[k], hk, an);
        }

        const float r = sigmoid_f(fmaf(xt, wihr, br) + ar);
        const float z = sigmoid_f(fmaf(xt, wihz, bz) + az);
        const float n = tanh_f(fmaf(xt, wihn, bin) + r * (an + bhn));
        h = fmaf(z, h - n, n);  // (1-z)*n + z*h

        // ---- rotate x chunks (uniform branch, off critical path) ----
        if (j == 63) {
            xcur = xnxt;
            const int idx = t + 65 + g;  // base of chunk after next
            xnxt = (idx < T_LEN) ? x[xbase + idx] : 0.0f;
        }
    }

    // ---- epilogue: out[b] = h . W_fc + b_fc (full-wave shuffle reduction) ----
    float v = h * W_fc[g];
#pragma unroll
    for (int off = 32; off > 0; off >>= 1) v += __shfl_down(v, off);
    if (g == 0) out[b] = v + b_fc[0];
}

extern "C" void kernel_launch(void* const* d_in, const int* in_sizes, int n_in,
                              void* d_out, int out_size, void* d_ws, size_t ws_size,
                              hipStream_t stream) {
    const float* x    = (const float*)d_in[0];
    const float* W_ih = (const float*)d_in[1];
    const float* W_hh = (const float*)d_in[2];
    const float* b_ih = (const float*)d_in[3];
    const float* b_hh = (const float*)d_in[4];
    const float* W_fc = (const float*)d_in[5];
    const float* b_fc = (const float*)d_in[6];
    float* out = (float*)d_out;

    const int B = 256;  // in_sizes[0] = B*T = 768000 -> B=256, T=3000
    gru_onewave<<<B, 64, 0, stream>>>(x, W_ih, W_hh, b_ih, b_hh, W_fc, b_fc, out);
}

// Round 3
// 1285.556 us; speedup vs baseline: 1.3624x; 1.3624x over previous
//
#include <hip/hip_runtime.h>
#include <math.h>

#define T_LEN 3000
#define HID 64

typedef float v2f __attribute__((ext_vector_type(2)));

__device__ __forceinline__ float sigmoid_f(float v) {
    return __builtin_amdgcn_rcpf(1.0f + __expf(-v));
}
__device__ __forceinline__ float tanh_f(float v) {
    return fmaf(2.0f, __builtin_amdgcn_rcpf(1.0f + __expf(-2.0f * v)), -1.0f);
}

// One wave per batch element, zero barriers.
// Lane g owns hidden unit g: W_hh rows g / 64+g / 128+g live in 192 VGPRs as
// float2 pairs (v_pk_fma_f32). h is broadcast through LDS: lane g writes h[g],
// all lanes re-read via 16x ds_read_b128. Single-wave DS ops complete in
// order (lgkmcnt is in-order), so no s_barrier is needed — only a
// compile-time wave_barrier to pin the write/read ordering.
__global__ __launch_bounds__(64, 1) void gru_pk(
    const float* __restrict__ x,     // (B, T, 1)
    const float* __restrict__ W_ih,  // (192, 1)
    const float* __restrict__ W_hh,  // (192, 64)
    const float* __restrict__ b_ih,  // (192,)
    const float* __restrict__ b_hh,  // (192,)
    const float* __restrict__ W_fc,  // (1, 64)
    const float* __restrict__ b_fc,  // (1,)
    float* __restrict__ out)         // (B,)
{
    const int b = blockIdx.x;
    const int g = threadIdx.x;  // 0..63, hidden unit index
    const long xbase = (long)b * T_LEN;

    __shared__ __align__(16) float h_lds[HID];
    __shared__ float x_lds[64];

    // ---- one-time: W_hh rows for unit g -> 96 float2 (192 VGPRs) ----
    v2f wr[32], wz[32], wn[32];
    const float4* Wr4 = reinterpret_cast<const float4*>(W_hh + (size_t)(g)       * HID);
    const float4* Wz4 = reinterpret_cast<const float4*>(W_hh + (size_t)(64 + g)  * HID);
    const float4* Wn4 = reinterpret_cast<const float4*>(W_hh + (size_t)(128 + g) * HID);
#pragma unroll
    for (int i = 0; i < 16; ++i) {
        float4 a = Wr4[i]; wr[2*i] = (v2f){a.x, a.y}; wr[2*i+1] = (v2f){a.z, a.w};
        float4 c = Wz4[i]; wz[2*i] = (v2f){c.x, c.y}; wz[2*i+1] = (v2f){c.z, c.w};
        float4 d = Wn4[i]; wn[2*i] = (v2f){d.x, d.y}; wn[2*i+1] = (v2f){d.z, d.w};
    }
    const float wihr = W_ih[g],        wihz = W_ih[64 + g],   wihn = W_ih[128 + g];
    const float br   = b_ih[g]      + b_hh[g];
    const float bz   = b_ih[64 + g] + b_hh[64 + g];
    const float bin  = b_ih[128 + g];
    const float bhn  = b_hh[128 + g];

    // init h and first x chunk (single wave: DS in-order, no barrier needed)
    h_lds[g] = 0.0f;
    x_lds[g] = x[xbase + g];
    float xnxt = (64 + g < T_LEN) ? x[xbase + 64 + g] : 0.0f;
    float h = 0.0f;  // lane g holds h[g]
    __builtin_amdgcn_wave_barrier();

    const float4* h4 = reinterpret_cast<const float4*>(h_lds);

    for (int t = 0; t < T_LEN; ++t) {
        const int j = t & 63;

        // ---- matvec: 96 v_pk_fma_f32, broadcast LDS reads ----
        v2f ar0 = {0.f, 0.f}, ar1 = {0.f, 0.f};
        v2f az0 = {0.f, 0.f}, az1 = {0.f, 0.f};
        v2f an0 = {0.f, 0.f}, an1 = {0.f, 0.f};
#pragma unroll
        for (int i = 0; i < 16; ++i) {
            const float4 hq = h4[i];
            const v2f h01 = (v2f){hq.x, hq.y};
            const v2f h23 = (v2f){hq.z, hq.w};
            ar0 += wr[2*i] * h01;  ar1 += wr[2*i+1] * h23;
            az0 += wz[2*i] * h01;  az1 += wz[2*i+1] * h23;
            an0 += wn[2*i] * h01;  an1 += wn[2*i+1] * h23;
        }
        const v2f arv = ar0 + ar1, azv = az0 + az1, anv = an0 + an1;
        const float ar = arv.x + arv.y;
        const float az = azv.x + azv.y;
        const float an = anv.x + anv.y;

        const float xt = x_lds[j];
        const float r = sigmoid_f(fmaf(xt, wihr, br) + ar);
        const float z = sigmoid_f(fmaf(xt, wihz, bz) + az);
        const float n = tanh_f(fmaf(xt, wihn, bin) + r * (an + bhn));
        h = fmaf(z, h - n, n);  // (1-z)*n + z*h

        __builtin_amdgcn_wave_barrier();
        h_lds[g] = h;
        if (j == 63) {
            x_lds[g] = xnxt;
            const int idx = t + 65 + g;  // chunk after next
            xnxt = (idx < T_LEN) ? x[xbase + idx] : 0.0f;
        }
        __builtin_amdgcn_wave_barrier();
    }

    // ---- epilogue: out[b] = h . W_fc + b_fc ----
    float v = h * W_fc[g];
#pragma unroll
    for (int off = 32; off > 0; off >>= 1) v += __shfl_down(v, off);
    if (g == 0) out[b] = v + b_fc[0];
}

extern "C" void kernel_launch(void* const* d_in, const int* in_sizes, int n_in,
                              void* d_out, int out_size, void* d_ws, size_t ws_size,
                              hipStream_t stream) {
    const float* x    = (const float*)d_in[0];
    const float* W_ih = (const float*)d_in[1];
    const float* W_hh = (const float*)d_in[2];
    const float* b_ih = (const float*)d_in[3];
    const float* b_hh = (const float*)d_in[4];
    const float* W_fc = (const float*)d_in[5];
    const float* b_fc = (const float*)d_in[6];
    float* out = (float*)d_out;

    const int B = 256;  // in_sizes[0] = B*T = 768000 -> B=256, T=3000
    gru_pk<<<B, 64, 0, stream>>>(x, W_ih, W_hh, b_ih, b_hh, W_fc, b_fc, out);
}

// Round 4
// 1275.078 us; speedup vs baseline: 1.3736x; 1.0082x over previous
//
#include <hip/hip_runtime.h>
#include <math.h>

#define T_LEN 3000
#define HID 64

typedef float v2f __attribute__((ext_vector_type(2)));

__device__ __forceinline__ float sigmoid_f(float v) {
    return __builtin_amdgcn_rcpf(1.0f + __expf(-v));
}
__device__ __forceinline__ float tanh_f(float v) {
    return fmaf(2.0f, __builtin_amdgcn_rcpf(1.0f + __expf(-2.0f * v)), -1.0f);
}

// One wave per batch element, zero s_barriers.
// Lane g owns hidden unit g: W_hh rows g / 64+g / 128+g live in 192 VGPRs as
// float2 pairs (v_pk_fma_f32), PINNED via empty inline-asm so the register
// allocator cannot rematerialize the loads inside the loop (R3 bug: VGPR=120
// with 192 weights declared -> per-step L1/L2 refetch). h is broadcast
// through LDS (write h[g], re-read 16x ds_read_b128); single-wave DS ops are
// in-order, so only compile-time wave_barriers are needed.
__global__ __launch_bounds__(64, 1) void gru_pin(
    const float* __restrict__ x,     // (B, T, 1)
    const float* __restrict__ W_ih,  // (192, 1)
    const float* __restrict__ W_hh,  // (192, 64)
    const float* __restrict__ b_ih,  // (192,)
    const float* __restrict__ b_hh,  // (192,)
    const float* __restrict__ W_fc,  // (1, 64)
    const float* __restrict__ b_fc,  // (1,)
    float* __restrict__ out)         // (B,)
{
    const int b = blockIdx.x;
    const int g = threadIdx.x;  // 0..63, hidden unit index
    const long xbase = (long)b * T_LEN;

    __shared__ __align__(16) float h_lds[HID];
    __shared__ float x_lds[64];

    // ---- one-time: W_hh rows for unit g -> 96 float2 (192 VGPRs) ----
    v2f wr[32], wz[32], wn[32];
    const float4* Wr4 = reinterpret_cast<const float4*>(W_hh + (size_t)(g)       * HID);
    const float4* Wz4 = reinterpret_cast<const float4*>(W_hh + (size_t)(64 + g)  * HID);
    const float4* Wn4 = reinterpret_cast<const float4*>(W_hh + (size_t)(128 + g) * HID);
#pragma unroll
    for (int i = 0; i < 16; ++i) {
        float4 a = Wr4[i]; wr[2*i] = (v2f){a.x, a.y}; wr[2*i+1] = (v2f){a.z, a.w};
        float4 c = Wz4[i]; wz[2*i] = (v2f){c.x, c.y}; wz[2*i+1] = (v2f){c.z, c.w};
        float4 d = Wn4[i]; wn[2*i] = (v2f){d.x, d.y}; wn[2*i+1] = (v2f){d.z, d.w};
    }
    // Pin: INLINEASM defs are not rematerializable -> weights stay in VGPRs.
#pragma unroll
    for (int i = 0; i < 32; ++i) {
        asm volatile("" : "+v"(wr[i]), "+v"(wz[i]), "+v"(wn[i]));
    }

    const float wihr = W_ih[g],        wihz = W_ih[64 + g],   wihn = W_ih[128 + g];
    const float br   = b_ih[g]      + b_hh[g];
    const float bz   = b_ih[64 + g] + b_hh[64 + g];
    const float bin  = b_ih[128 + g];
    const float bhn  = b_hh[128 + g];

    // init h and first x chunk (single wave: DS in-order, no barrier needed)
    h_lds[g] = 0.0f;
    x_lds[g] = x[xbase + g];
    float xnxt = (64 + g < T_LEN) ? x[xbase + 64 + g] : 0.0f;
    float h = 0.0f;  // lane g holds h[g]
    __builtin_amdgcn_wave_barrier();

    const float4* h4 = reinterpret_cast<const float4*>(h_lds);

    for (int t = 0; t < T_LEN; ++t) {
        const int j = t & 63;

        // ---- matvec: 96 v_pk_fma_f32, broadcast LDS reads ----
        v2f ar0 = {0.f, 0.f}, ar1 = {0.f, 0.f};
        v2f az0 = {0.f, 0.f}, az1 = {0.f, 0.f};
        v2f an0 = {0.f, 0.f}, an1 = {0.f, 0.f};
#pragma unroll
        for (int i = 0; i < 16; ++i) {
            const float4 hq = h4[i];
            const v2f h01 = (v2f){hq.x, hq.y};
            const v2f h23 = (v2f){hq.z, hq.w};
            ar0 += wr[2*i] * h01;  ar1 += wr[2*i+1] * h23;
            az0 += wz[2*i] * h01;  az1 += wz[2*i+1] * h23;
            an0 += wn[2*i] * h01;  an1 += wn[2*i+1] * h23;
        }
        const v2f arv = ar0 + ar1, azv = az0 + az1, anv = an0 + an1;
        const float ar = arv.x + arv.y;
        const float az = azv.x + azv.y;
        const float an = anv.x + anv.y;

        const float xt = x_lds[j];
        const float r = sigmoid_f(fmaf(xt, wihr, br) + ar);
        const float z = sigmoid_f(fmaf(xt, wihz, bz) + az);
        const float n = tanh_f(fmaf(xt, wihn, bin) + r * (an + bhn));
        h = fmaf(z, h - n, n);  // (1-z)*n + z*h

        __builtin_amdgcn_wave_barrier();
        h_lds[g] = h;
        if (j == 63) {
            x_lds[g] = xnxt;
            const int idx = t + 65 + g;  // chunk after next
            xnxt = (idx < T_LEN) ? x[xbase + idx] : 0.0f;
        }
        __builtin_amdgcn_wave_barrier();
    }

    // ---- epilogue: out[b] = h . W_fc + b_fc ----
    float v = h * W_fc[g];
#pragma unroll
    for (int off = 32; off > 0; off >>= 1) v += __shfl_down(v, off);
    if (g == 0) out[b] = v + b_fc[0];
}

extern "C" void kernel_launch(void* const* d_in, const int* in_sizes, int n_in,
                              void* d_out, int out_size, void* d_ws, size_t ws_size,
                              hipStream_t stream) {
    const float* x    = (const float*)d_in[0];
    const float* W_ih = (const float*)d_in[1];
    const float* W_hh = (const float*)d_in[2];
    const float* b_ih = (const float*)d_in[3];
    const float* b_hh = (const float*)d_in[4];
    const float* W_fc = (const float*)d_in[5];
    const float* b_fc = (const float*)d_in[6];
    float* out = (float*)d_out;

    const int B = 256;  // in_sizes[0] = B*T = 768000 -> B=256, T=3000
    gru_pin<<<B, 64, 0, stream>>>(x, W_ih, W_hh, b_ih, b_hh, W_fc, b_fc, out);
}

// Round 5
// 1071.637 us; speedup vs baseline: 1.6344x; 1.1898x over previous
//
#include <hip/hip_runtime.h>
#include <math.h>

#define T_LEN 3000
#define HID 64

typedef _Float16 f16;
typedef f16 h2 __attribute__((ext_vector_type(2)));

__device__ __forceinline__ float sigmoid_f(float v) {
    return __builtin_amdgcn_rcpf(1.0f + __expf(-v));
}
__device__ __forceinline__ float tanh_f(float v) {
    return fmaf(2.0f, __builtin_amdgcn_rcpf(1.0f + __expf(-2.0f * v)), -1.0f);
}

// One wave per batch element, zero s_barriers.
// R4 post-mortem: 192 fp32 weight VGPRs + 64 VGPRs of hoisted h reads never
// fit in the file -> allocator spilled every step. R5: weights stored as f16
// pairs (96 VGPRs) and multiplied with v_dot2_f32_f16 (fp32 accumulate), h
// broadcast through LDS as f16 (8x ds_read_b128 instead of 16). Carried h
// stays fp32 in-register; only matvec inputs are rounded (rel 4.9e-4 -> out
// err ~1e-3 << 3.1e-3 threshold).
__global__ __launch_bounds__(64, 1) void gru_dot2(
    const float* __restrict__ x,     // (B, T, 1)
    const float* __restrict__ W_ih,  // (192, 1)
    const float* __restrict__ W_hh,  // (192, 64)
    const float* __restrict__ b_ih,  // (192,)
    const float* __restrict__ b_hh,  // (192,)
    const float* __restrict__ W_fc,  // (1, 64)
    const float* __restrict__ b_fc,  // (1,)
    float* __restrict__ out)         // (B,)
{
    const int b = blockIdx.x;
    const int g = threadIdx.x;  // 0..63, hidden unit index
    const long xbase = (long)b * T_LEN;

    __shared__ __align__(16) f16 h_lds[HID];   // 128 B: 8x float4 reads
    __shared__ float x_lds[64];

    // ---- one-time: W_hh rows for unit g -> f16 pairs (96 VGPRs total) ----
    h2 wr[32], wz[32], wn[32];
    {
        const float4* Wr4 = reinterpret_cast<const float4*>(W_hh + (size_t)(g)       * HID);
        const float4* Wz4 = reinterpret_cast<const float4*>(W_hh + (size_t)(64 + g)  * HID);
        const float4* Wn4 = reinterpret_cast<const float4*>(W_hh + (size_t)(128 + g) * HID);
#pragma unroll
        for (int i = 0; i < 16; ++i) {
            float4 a = Wr4[i];
            h2 t0; t0.x = (f16)a.x; t0.y = (f16)a.y; wr[2*i]   = t0;
            h2 t1; t1.x = (f16)a.z; t1.y = (f16)a.w; wr[2*i+1] = t1;
            float4 c = Wz4[i];
            h2 t2; t2.x = (f16)c.x; t2.y = (f16)c.y; wz[2*i]   = t2;
            h2 t3; t3.x = (f16)c.z; t3.y = (f16)c.w; wz[2*i+1] = t3;
            float4 d = Wn4[i];
            h2 t4; t4.x = (f16)d.x; t4.y = (f16)d.y; wn[2*i]   = t4;
            h2 t5; t5.x = (f16)d.z; t5.y = (f16)d.w; wn[2*i+1] = t5;
        }
    }
#pragma unroll
    for (int i = 0; i < 32; ++i) {
        asm volatile("" : "+v"(wr[i]), "+v"(wz[i]), "+v"(wn[i]));
    }

    const float wihr = W_ih[g],        wihz = W_ih[64 + g],   wihn = W_ih[128 + g];
    const float br   = b_ih[g]      + b_hh[g];
    const float bz   = b_ih[64 + g] + b_hh[64 + g];
    const float bin  = b_ih[128 + g];
    const float bhn  = b_hh[128 + g];

    // init h and first x chunk (single wave: DS in-order, no barrier needed)
    h_lds[g] = (f16)0.0f;
    x_lds[g] = x[xbase + g];
    float xnxt = (64 + g < T_LEN) ? x[xbase + 64 + g] : 0.0f;
    float h = 0.0f;  // lane g holds h[g] in fp32
    __builtin_amdgcn_wave_barrier();

    const float4* h4 = reinterpret_cast<const float4*>(h_lds);  // 8 x (8 halves)

    for (int t = 0; t < T_LEN; ++t) {
        const int j = t & 63;

        // ---- matvec: 96 v_dot2_f32_f16, broadcast LDS reads (8x b128) ----
        float ar0 = 0.f, ar1 = 0.f, az0 = 0.f, az1 = 0.f, an0 = 0.f, an1 = 0.f;
#pragma unroll
        for (int i = 0; i < 8; ++i) {
            union { float4 f; h2 h[4]; } u;
            u.f = h4[i];
            ar0 = __builtin_amdgcn_fdot2(wr[4*i+0], u.h[0], ar0, false);
            az0 = __builtin_amdgcn_fdot2(wz[4*i+0], u.h[0], az0, false);
            an0 = __builtin_amdgcn_fdot2(wn[4*i+0], u.h[0], an0, false);
            ar0 = __builtin_amdgcn_fdot2(wr[4*i+1], u.h[1], ar0, false);
            az0 = __builtin_amdgcn_fdot2(wz[4*i+1], u.h[1], az0, false);
            an0 = __builtin_amdgcn_fdot2(wn[4*i+1], u.h[1], an0, false);
            ar1 = __builtin_amdgcn_fdot2(wr[4*i+2], u.h[2], ar1, false);
            az1 = __builtin_amdgcn_fdot2(wz[4*i+2], u.h[2], az1, false);
            an1 = __builtin_amdgcn_fdot2(wn[4*i+2], u.h[2], an1, false);
            ar1 = __builtin_amdgcn_fdot2(wr[4*i+3], u.h[3], ar1, false);
            az1 = __builtin_amdgcn_fdot2(wz[4*i+3], u.h[3], az1, false);
            an1 = __builtin_amdgcn_fdot2(wn[4*i+3], u.h[3], an1, false);
        }
        const float ar = ar0 + ar1;
        const float az = az0 + az1;
        const float an = an0 + an1;

        const float xt = x_lds[j];
        const float r = sigmoid_f(fmaf(xt, wihr, br) + ar);
        const float z = sigmoid_f(fmaf(xt, wihz, bz) + az);
        const float n = tanh_f(fmaf(xt, wihn, bin) + r * (an + bhn));
        h = fmaf(z, h - n, n);  // (1-z)*n + z*h

        __builtin_amdgcn_wave_barrier();
        h_lds[g] = (f16)h;
        if (j == 63) {
            x_lds[g] = xnxt;
            const int idx = t + 65 + g;  // chunk after next
            xnxt = (idx < T_LEN) ? x[xbase + idx] : 0.0f;
        }
        __builtin_amdgcn_wave_barrier();
    }

    // ---- epilogue: out[b] = h . W_fc + b_fc (fp32) ----
    float v = h * W_fc[g];
#pragma unroll
    for (int off = 32; off > 0; off >>= 1) v += __shfl_down(v, off);
    if (g == 0) out[b] = v + b_fc[0];
}

extern "C" void kernel_launch(void* const* d_in, const int* in_sizes, int n_in,
                              void* d_out, int out_size, void* d_ws, size_t ws_size,
                              hipStream_t stream) {
    const float* x    = (const float*)d_in[0];
    const float* W_ih = (const float*)d_in[1];
    const float* W_hh = (const float*)d_in[2];
    const float* b_ih = (const float*)d_in[3];
    const float* b_hh = (const float*)d_in[4];
    const float* W_fc = (const float*)d_in[5];
    const float* b_fc = (const float*)d_in[6];
    float* out = (float*)d_out;

    const int B = 256;  // in_sizes[0] = B*T = 768000 -> B=256, T=3000
    gru_dot2<<<B, 64, 0, stream>>>(x, W_ih, W_hh, b_ih, b_hh, W_fc, b_fc, out);
}

// Round 6
// 1025.511 us; speedup vs baseline: 1.7079x; 1.0450x over previous
//
#include <hip/hip_runtime.h>
#include <math.h>

#define T_LEN 3000
#define HID 64

typedef _Float16 f16;
typedef f16 h2 __attribute__((ext_vector_type(2)));

__device__ __forceinline__ float sigmoid_f(float v) {
    return __builtin_amdgcn_rcpf(1.0f + __expf(-v));
}
__device__ __forceinline__ float tanh_f(float v) {
    return fmaf(2.0f, __builtin_amdgcn_rcpf(1.0f + __expf(-2.0f * v)), -1.0f);
}

// One wave per batch element, zero s_barriers.
// R5 post-mortem: VGPR_Count=76 < 96 declared weight regs -> allocator kept
// weights in AGPRs (gfx950 unified file) and paid ~96 v_accvgpr_read/step.
// R6: pin occupancy to 1 wave/EU via amdgpu_waves_per_eu(1,1) so the backend
// has no occupancy incentive to shrink the arch-VGPR budget; weights (f16
// pairs, 96 VGPRs) should become truly register-resident. Matvec via
// v_dot2_f32_f16 (fp32 accumulate); h broadcast through LDS as f16
// (8x ds_read_b128); single-wave in-order DS -> only wave_barriers.
__global__
__attribute__((amdgpu_flat_work_group_size(64, 64), amdgpu_waves_per_eu(1, 1)))
void gru_dot2(
    const float* __restrict__ x,     // (B, T, 1)
    const float* __restrict__ W_ih,  // (192, 1)
    const float* __restrict__ W_hh,  // (192, 64)
    const float* __restrict__ b_ih,  // (192,)
    const float* __restrict__ b_hh,  // (192,)
    const float* __restrict__ W_fc,  // (1, 64)
    const float* __restrict__ b_fc,  // (1,)
    float* __restrict__ out)         // (B,)
{
    const int b = blockIdx.x;
    const int g = threadIdx.x;  // 0..63, hidden unit index
    const long xbase = (long)b * T_LEN;

    __shared__ __align__(16) f16 h_lds[HID];   // 128 B: 8x float4 reads
    __shared__ float x_lds[64];

    // ---- one-time: W_hh rows for unit g -> f16 pairs (96 VGPRs total) ----
    h2 wr[32], wz[32], wn[32];
    {
        const float4* Wr4 = reinterpret_cast<const float4*>(W_hh + (size_t)(g)       * HID);
        const float4* Wz4 = reinterpret_cast<const float4*>(W_hh + (size_t)(64 + g)  * HID);
        const float4* Wn4 = reinterpret_cast<const float4*>(W_hh + (size_t)(128 + g) * HID);
#pragma unroll
        for (int i = 0; i < 16; ++i) {
            float4 a = Wr4[i];
            h2 t0; t0.x = (f16)a.x; t0.y = (f16)a.y; wr[2*i]   = t0;
            h2 t1; t1.x = (f16)a.z; t1.y = (f16)a.w; wr[2*i+1] = t1;
            float4 c = Wz4[i];
            h2 t2; t2.x = (f16)c.x; t2.y = (f16)c.y; wz[2*i]   = t2;
            h2 t3; t3.x = (f16)c.z; t3.y = (f16)c.w; wz[2*i+1] = t3;
            float4 d = Wn4[i];
            h2 t4; t4.x = (f16)d.x; t4.y = (f16)d.y; wn[2*i]   = t4;
            h2 t5; t5.x = (f16)d.z; t5.y = (f16)d.w; wn[2*i+1] = t5;
        }
    }
#pragma unroll
    for (int i = 0; i < 32; ++i) {
        asm volatile("" : "+v"(wr[i]), "+v"(wz[i]), "+v"(wn[i]));
    }

    const float wihr = W_ih[g],        wihz = W_ih[64 + g],   wihn = W_ih[128 + g];
    const float br   = b_ih[g]      + b_hh[g];
    const float bz   = b_ih[64 + g] + b_hh[64 + g];
    const float bin  = b_ih[128 + g];
    const float bhn  = b_hh[128 + g];

    // init h and first x chunk (single wave: DS in-order, no barrier needed)
    h_lds[g] = (f16)0.0f;
    x_lds[g] = x[xbase + g];
    float xnxt = (64 + g < T_LEN) ? x[xbase + 64 + g] : 0.0f;
    float h = 0.0f;  // lane g holds h[g] in fp32
    __builtin_amdgcn_wave_barrier();

    const float4* h4 = reinterpret_cast<const float4*>(h_lds);  // 8 x (8 halves)

    for (int t = 0; t < T_LEN; ++t) {
        const int j = t & 63;

        // ---- matvec: 96 v_dot2_f32_f16, broadcast LDS reads (8x b128) ----
        float ar0 = 0.f, ar1 = 0.f, az0 = 0.f, az1 = 0.f, an0 = 0.f, an1 = 0.f;
#pragma unroll
        for (int i = 0; i < 8; ++i) {
            union { float4 f; h2 h[4]; } u;
            u.f = h4[i];
            ar0 = __builtin_amdgcn_fdot2(wr[4*i+0], u.h[0], ar0, false);
            az0 = __builtin_amdgcn_fdot2(wz[4*i+0], u.h[0], az0, false);
            an0 = __builtin_amdgcn_fdot2(wn[4*i+0], u.h[0], an0, false);
            ar0 = __builtin_amdgcn_fdot2(wr[4*i+1], u.h[1], ar0, false);
            az0 = __builtin_amdgcn_fdot2(wz[4*i+1], u.h[1], az0, false);
            an0 = __builtin_amdgcn_fdot2(wn[4*i+1], u.h[1], an0, false);
            ar1 = __builtin_amdgcn_fdot2(wr[4*i+2], u.h[2], ar1, false);
            az1 = __builtin_amdgcn_fdot2(wz[4*i+2], u.h[2], az1, false);
            an1 = __builtin_amdgcn_fdot2(wn[4*i+2], u.h[2], an1, false);
            ar1 = __builtin_amdgcn_fdot2(wr[4*i+3], u.h[3], ar1, false);
            az1 = __builtin_amdgcn_fdot2(wz[4*i+3], u.h[3], az1, false);
            an1 = __builtin_amdgcn_fdot2(wn[4*i+3], u.h[3], an1, false);
        }
        const float ar = ar0 + ar1;
        const float az = az0 + az1;
        const float an = an0 + an1;

        const float xt = x_lds[j];
        const float r = sigmoid_f(fmaf(xt, wihr, br) + ar);
        const float z = sigmoid_f(fmaf(xt, wihz, bz) + az);
        const float n = tanh_f(fmaf(xt, wihn, bin) + r * (an + bhn));
        h = fmaf(z, h - n, n);  // (1-z)*n + z*h

        __builtin_amdgcn_wave_barrier();
        h_lds[g] = (f16)h;
        if (j == 63) {
            x_lds[g] = xnxt;
            const int idx = t + 65 + g;  // chunk after next
            xnxt = (idx < T_LEN) ? x[xbase + idx] : 0.0f;
        }
        __builtin_amdgcn_wave_barrier();
    }

    // ---- epilogue: out[b] = h . W_fc + b_fc (fp32) ----
    float v = h * W_fc[g];
#pragma unroll
    for (int off = 32; off > 0; off >>= 1) v += __shfl_down(v, off);
    if (g == 0) out[b] = v + b_fc[0];
}

extern "C" void kernel_launch(void* const* d_in, const int* in_sizes, int n_in,
                              void* d_out, int out_size, void* d_ws, size_t ws_size,
                              hipStream_t stream) {
    const float* x    = (const float*)d_in[0];
    const float* W_ih = (const float*)d_in[1];
    const float* W_hh = (const float*)d_in[2];
    const float* b_ih = (const float*)d_in[3];
    const float* b_hh = (const float*)d_in[4];
    const float* W_fc = (const float*)d_in[5];
    const float* b_fc = (const float*)d_in[6];
    float* out = (float*)d_out;

    const int B = 256;  // in_sizes[0] = B*T = 768000 -> B=256, T=3000
    gru_dot2<<<B, 64, 0, stream>>>(x, W_ih, W_hh, b_ih, b_hh, W_fc, b_fc, out);
}